// Round 1
// baseline (510.523 us; speedup 1.0000x reference)
//
#include <hip/hip_runtime.h>

// TopK (K=64) per row, B=4096 x D=16384 fp32.
// out = zeros; out[row, top64 idx] = value.
//
// R3: register-resident row (8 x uint4 = 32 VGPR/thread), replacing the LDS
// staging + 3-pass radix of R2. Single 2048-bin histogram over the top 11
// ordered-uint bits finds the threshold bin; that bin holds only ~55 elements
// for N(0,1) rows (bin width 0.25 around z~2.66), so the exact 64th-largest is
// resolved by compacting those candidates to a small LDS list and doing an
// O(C^2) rank select. LDS drops 73 KiB -> ~17 KiB, launch_bounds(512,6)
// targets 3 blocks/CU so HBM stays busy while other blocks are in their
// select phase. Ties at threshold resolved lowest-index-first (lax.top_k).

#define TK_D      16384
#define TK_K      64
#define TK_BLOCK  512
#define TK_NV     8            // uint4 chunks per thread (TK_D/4/TK_BLOCK)
#define TK_BINS   2048
#define TK_CAP    1024         // threshold-bin candidate cap (expected ~55)

__device__ __forceinline__ unsigned ord_map(unsigned b) {
    // larger u <=> larger float (handles negatives)
    return b ^ ((unsigned)((int)b >> 31) | 0x80000000u);
}
__device__ __forceinline__ unsigned ord_inv(unsigned u) {
    // inverse of ord_map
    return u ^ ((unsigned)((int)(~u) >> 31) | 0x80000000u);
}

__launch_bounds__(TK_BLOCK, 6)
__global__ void topk_scatter_kernel(const float* __restrict__ x,
                                    float* __restrict__ out) {
    __shared__ int      sh_hist[TK_BINS];    // 8 KiB
    __shared__ int      sh_wsum[8];
    __shared__ unsigned sh_cu[TK_CAP];       // candidate ordered-uints, 4 KiB
    __shared__ int      sh_cidx[TK_CAP];     // candidate columns, 4 KiB
    __shared__ int      sh_bin;
    __shared__ int      sh_rem;
    __shared__ int      sh_cnt;
    __shared__ unsigned sh_T;
    __shared__ int      sh_need;

    const int row  = blockIdx.x;
    const int tid  = threadIdx.x;
    const int lane = tid & 63;
    const int wv   = tid >> 6;

    // ---- coalesced global -> register load (issued first, hides latency
    //      under hist zeroing; barrier drains vmcnt before first use) ----
    const uint4* __restrict__ xr = (const uint4*)(x + (size_t)row * TK_D);
    uint4 r[TK_NV];
    #pragma unroll
    for (int i = 0; i < TK_NV; i++) r[i] = xr[tid + i * TK_BLOCK];

    ((int4*)sh_hist)[tid] = int4{0, 0, 0, 0};          // zero 4 bins/thread
    if (tid == 0) sh_cnt = 0;
    __syncthreads();

    // ---- histogram of top-11 ordered bits ----
    #pragma unroll
    for (int i = 0; i < TK_NV; i++) {
        #pragma unroll
        for (int c = 0; c < 4; c++) {
            unsigned u = ord_map(((const unsigned*)&r[i])[c]);
            atomicAdd(&sh_hist[u >> 21], 1);
        }
    }
    __syncthreads();

    // ---- hierarchical suffix scan: thread t owns bins 4t..4t+3 ----
    int h0 = sh_hist[4 * tid + 0], h1 = sh_hist[4 * tid + 1];
    int h2 = sh_hist[4 * tid + 2], h3 = sh_hist[4 * tid + 3];
    int local = h0 + h1 + h2 + h3;
    int suf = local;                                   // sum over lanes >= lane
    #pragma unroll
    for (int off = 1; off < 64; off <<= 1) {
        int o = __shfl_down(suf, off);
        if (lane + off < 64) suf += o;
    }
    if (lane == 0) sh_wsum[wv] = suf;
    __syncthreads();

    int above = 0;                                     // bins above this wave
    #pragma unroll
    for (int w2 = 0; w2 < 8; w2++)
        if (w2 > wv) above += sh_wsum[w2];

    int a3 = above + (suf - local);                    // strictly above bin 4t+3
    int S3 = a3 + h3, S2 = S3 + h2, S1 = S2 + h1, S0 = S1 + h0;
    if      (S3 >= TK_K && a3 < TK_K) { sh_bin = 4 * tid + 3; sh_rem = TK_K - a3; }
    else if (S2 >= TK_K && S3 < TK_K) { sh_bin = 4 * tid + 2; sh_rem = TK_K - S3; }
    else if (S1 >= TK_K && S2 < TK_K) { sh_bin = 4 * tid + 1; sh_rem = TK_K - S2; }
    else if (S0 >= TK_K && S1 < TK_K) { sh_bin = 4 * tid + 0; sh_rem = TK_K - S1; }
    __syncthreads();

    const unsigned binv = (unsigned)sh_bin;
    const int      rem  = sh_rem;                      // 1..64

    // ---- compact threshold-bin candidates into tiny LDS list ----
    #pragma unroll
    for (int i = 0; i < TK_NV; i++) {
        #pragma unroll
        for (int c = 0; c < 4; c++) {
            unsigned u = ord_map(((const unsigned*)&r[i])[c]);
            if ((u >> 21) == binv) {
                int pos = atomicAdd(&sh_cnt, 1);
                if (pos < TK_CAP) {
                    sh_cu[pos]   = u;
                    sh_cidx[pos] = 4 * (tid + i * TK_BLOCK) + c;
                }
            }
        }
    }
    __syncthreads();

    // ---- exact rank select among candidates: T = rem-th largest ----
    const int C = min(sh_cnt, TK_CAP);
    for (int i = tid; i < C; i += TK_BLOCK) {
        unsigned ui = sh_cu[i];
        int abv = 0, eq = 0;
        for (int j = 0; j < C; j++) {
            unsigned uj = sh_cu[j];
            abv += (uj > ui);
            eq  += (uj == ui);
        }
        if (abv < rem && abv + eq >= rem) {            // same-value writers race benignly
            sh_T    = ui;
            sh_need = rem - abv;                       // ties to accept
        }
    }
    __syncthreads();

    const unsigned T    = sh_T;
    const int      need = sh_need;

    // ---- write pass from registers: val > T ? val : 0 ----
    float4* __restrict__ orow = (float4*)(out + (size_t)row * TK_D);
    #pragma unroll
    for (int i = 0; i < TK_NV; i++) {
        float4 o;
        #pragma unroll
        for (int c = 0; c < 4; c++) {
            unsigned raw = ((const unsigned*)&r[i])[c];
            unsigned u   = ord_map(raw);
            ((float*)&o)[c] = (u > T) ? __uint_as_float(raw) : 0.0f;
        }
        orow[tid + i * TK_BLOCK] = o;
    }
    __syncthreads();                                   // order stores vs tie fix

    // ---- accepted ties: lowest column indices first ----
    const float tval = __uint_as_float(ord_inv(T));
    for (int i = tid; i < C; i += TK_BLOCK) {
        if (sh_cu[i] == T) {
            int col  = sh_cidx[i];
            int rank = 0;
            for (int j = 0; j < C; j++)
                rank += (sh_cu[j] == T && sh_cidx[j] < col);
            if (rank < need)
                out[(size_t)row * TK_D + col] = tval;
        }
    }
}

extern "C" void kernel_launch(void* const* d_in, const int* in_sizes, int n_in,
                              void* d_out, int out_size, void* d_ws, size_t ws_size,
                              hipStream_t stream) {
    const float* x = (const float*)d_in[0];
    float* out = (float*)d_out;
    const int B = in_sizes[0] / TK_D;                  // 4096
    topk_scatter_kernel<<<B, TK_BLOCK, 0, stream>>>(x, out);
}

// Round 2
// 441.815 us; speedup vs baseline: 1.1555x; 1.1555x over previous
//
#include <hip/hip_runtime.h>

// TopK (K=64) per row, B=4096 x D=16384 fp32.
// out = zeros; out[row, top64 idx] = value.
//
// R4: R3's algorithm (register-resident row, single 2048-bin histogram over
// the top 11 ordered-uint bits, candidate compaction + O(C^2) exact select)
// with the spill fixed. R3's launch_bounds(512,6) capped VGPR at ~85 and the
// allocator spilled the 32-VGPR row to scratch (evidence: VGPR_Count=40,
// WRITE_SIZE 2.2x ideal = spill stores). launch_bounds(512,4) gives a
// 128-VGPR budget -> row stays in registers, 2 blocks/CU (16 waves/CU), same
// occupancy R2 ran at but with ~2 fewer full-row sweeps and fewer barriers.
// Registers hold the ord-mapped uint (monotone map of float); write pass
// inverts with ord_inv. Ties at threshold resolved lowest-index-first.

#define TK_D      16384
#define TK_K      64
#define TK_BLOCK  512
#define TK_NV     8            // uint4 chunks per thread (TK_D/4/TK_BLOCK)
#define TK_BINS   2048
#define TK_CAP    1024         // threshold-bin candidate cap (expected ~55)

__device__ __forceinline__ unsigned ord_map(unsigned b) {
    // larger u <=> larger float (handles negatives)
    return b ^ ((unsigned)((int)b >> 31) | 0x80000000u);
}
__device__ __forceinline__ unsigned ord_inv(unsigned u) {
    // inverse of ord_map
    return u ^ ((unsigned)((int)(~u) >> 31) | 0x80000000u);
}

__launch_bounds__(TK_BLOCK, 4)
__global__ void topk_scatter_kernel(const float* __restrict__ x,
                                    float* __restrict__ out) {
    __shared__ int      sh_hist[TK_BINS];    // 8 KiB
    __shared__ int      sh_wsum[8];
    __shared__ unsigned sh_cu[TK_CAP];       // candidate ordered-uints, 4 KiB
    __shared__ int      sh_cidx[TK_CAP];     // candidate columns, 4 KiB
    __shared__ int      sh_bin;
    __shared__ int      sh_rem;
    __shared__ int      sh_cnt;
    __shared__ unsigned sh_T;
    __shared__ int      sh_need;

    const int row  = blockIdx.x;
    const int tid  = threadIdx.x;
    const int lane = tid & 63;
    const int wv   = tid >> 6;

    // ---- coalesced global -> register load; ord_map applied in place so the
    //      resident state is the ordered uint (hist/compact use it directly) --
    const uint4* __restrict__ xr = (const uint4*)(x + (size_t)row * TK_D);
    uint4 r[TK_NV];
    #pragma unroll
    for (int i = 0; i < TK_NV; i++) r[i] = xr[tid + i * TK_BLOCK];

    ((int4*)sh_hist)[tid] = int4{0, 0, 0, 0};          // zero 4 bins/thread
    if (tid == 0) sh_cnt = 0;

    #pragma unroll
    for (int i = 0; i < TK_NV; i++) {
        r[i].x = ord_map(r[i].x);
        r[i].y = ord_map(r[i].y);
        r[i].z = ord_map(r[i].z);
        r[i].w = ord_map(r[i].w);
    }
    __syncthreads();

    // ---- histogram of top-11 ordered bits ----
    #pragma unroll
    for (int i = 0; i < TK_NV; i++) {
        #pragma unroll
        for (int c = 0; c < 4; c++) {
            unsigned u = ((const unsigned*)&r[i])[c];
            atomicAdd(&sh_hist[u >> 21], 1);
        }
    }
    __syncthreads();

    // ---- hierarchical suffix scan: thread t owns bins 4t..4t+3 ----
    int h0 = sh_hist[4 * tid + 0], h1 = sh_hist[4 * tid + 1];
    int h2 = sh_hist[4 * tid + 2], h3 = sh_hist[4 * tid + 3];
    int local = h0 + h1 + h2 + h3;
    int suf = local;                                   // sum over lanes >= lane
    #pragma unroll
    for (int off = 1; off < 64; off <<= 1) {
        int o = __shfl_down(suf, off);
        if (lane + off < 64) suf += o;
    }
    if (lane == 0) sh_wsum[wv] = suf;
    __syncthreads();

    int above = 0;                                     // bins above this wave
    #pragma unroll
    for (int w2 = 0; w2 < 8; w2++)
        if (w2 > wv) above += sh_wsum[w2];

    int a3 = above + (suf - local);                    // strictly above bin 4t+3
    int S3 = a3 + h3, S2 = S3 + h2, S1 = S2 + h1, S0 = S1 + h0;
    if      (S3 >= TK_K && a3 < TK_K) { sh_bin = 4 * tid + 3; sh_rem = TK_K - a3; }
    else if (S2 >= TK_K && S3 < TK_K) { sh_bin = 4 * tid + 2; sh_rem = TK_K - S3; }
    else if (S1 >= TK_K && S2 < TK_K) { sh_bin = 4 * tid + 1; sh_rem = TK_K - S2; }
    else if (S0 >= TK_K && S1 < TK_K) { sh_bin = 4 * tid + 0; sh_rem = TK_K - S1; }
    __syncthreads();

    const unsigned binv = (unsigned)sh_bin;
    const int      rem  = sh_rem;                      // 1..64

    // ---- compact threshold-bin candidates into tiny LDS list ----
    #pragma unroll
    for (int i = 0; i < TK_NV; i++) {
        #pragma unroll
        for (int c = 0; c < 4; c++) {
            unsigned u = ((const unsigned*)&r[i])[c];
            if ((u >> 21) == binv) {
                int pos = atomicAdd(&sh_cnt, 1);
                if (pos < TK_CAP) {
                    sh_cu[pos]   = u;
                    sh_cidx[pos] = 4 * (tid + i * TK_BLOCK) + c;
                }
            }
        }
    }
    __syncthreads();

    // ---- exact rank select among candidates: T = rem-th largest ----
    const int C = min(sh_cnt, TK_CAP);
    for (int i = tid; i < C; i += TK_BLOCK) {
        unsigned ui = sh_cu[i];
        int abv = 0, eq = 0;
        for (int j = 0; j < C; j++) {
            unsigned uj = sh_cu[j];
            abv += (uj > ui);
            eq  += (uj == ui);
        }
        if (abv < rem && abv + eq >= rem) {            // same-value writers race benignly
            sh_T    = ui;
            sh_need = rem - abv;                       // ties to accept
        }
    }
    __syncthreads();

    const unsigned T    = sh_T;
    const int      need = sh_need;

    // ---- write pass from registers: u > T ? ord_inv(u) : 0 ----
    float4* __restrict__ orow = (float4*)(out + (size_t)row * TK_D);
    #pragma unroll
    for (int i = 0; i < TK_NV; i++) {
        float4 o;
        #pragma unroll
        for (int c = 0; c < 4; c++) {
            unsigned u = ((const unsigned*)&r[i])[c];
            ((float*)&o)[c] = (u > T) ? __uint_as_float(ord_inv(u)) : 0.0f;
        }
        orow[tid + i * TK_BLOCK] = o;
    }
    __syncthreads();                                   // order stores vs tie fix

    // ---- accepted ties: lowest column indices first ----
    const float tval = __uint_as_float(ord_inv(T));
    for (int i = tid; i < C; i += TK_BLOCK) {
        if (sh_cu[i] == T) {
            int col  = sh_cidx[i];
            int rank = 0;
            for (int j = 0; j < C; j++)
                rank += (sh_cu[j] == T && sh_cidx[j] < col);
            if (rank < need)
                out[(size_t)row * TK_D + col] = tval;
        }
    }
}

extern "C" void kernel_launch(void* const* d_in, const int* in_sizes, int n_in,
                              void* d_out, int out_size, void* d_ws, size_t ws_size,
                              hipStream_t stream) {
    const float* x = (const float*)d_in[0];
    float* out = (float*)d_out;
    const int B = in_sizes[0] / TK_D;                  // 4096
    topk_scatter_kernel<<<B, TK_BLOCK, 0, stream>>>(x, out);
}